// Round 1
// baseline (861.930 us; speedup 1.0000x reference)
//
#include <hip/hip_runtime.h>
#include <stdint.h>

// ---------------------------------------------------------------------------
// TransformerBlock bf16 MFMA. OUTPUT FP32.
// Round 8: 256x256x64 8-phase GEMM (learn_hip m201 template, plain HIP):
// 8 waves (2Mx4N), wave tile 128x64, per-phase {ds_read || stage-issue ->
// s_barrier -> lgkmcnt(0) -> setprio(1) 16xMFMA setprio(0) -> s_barrier},
// counted s_waitcnt vmcnt(4) once per K-tile (A prefetch +1 tile @p1/p2,
// B prefetch +2 tiles @p4 after its last reader's barrier). XOR-8 LDS
// swizzle kept (bank-conflict-free, verified). N=2752 padded to 2816.
// ---------------------------------------------------------------------------

using bf16x8 = __attribute__((ext_vector_type(8))) short;
using f32x4  = __attribute__((ext_vector_type(4))) float;

typedef __attribute__((address_space(3))) uint16_t lds16_t;

__device__ __forceinline__ float bf2f(uint16_t h) {
  union { uint32_t u; float f; } v; v.u = ((uint32_t)h) << 16; return v.f;
}
__device__ __forceinline__ uint16_t f2bf(float f) {
  union { float f; uint32_t u; } v; v.f = f;
  uint32_t r = v.u + 0x7FFFu + ((v.u >> 16) & 1u);
  return (uint16_t)(r >> 16);
}
__device__ __forceinline__ float silu(float x) { return x / (1.0f + __expf(-x)); }

__device__ __forceinline__ void gload16(const uint16_t* g, lds16_t* l) {
  __builtin_amdgcn_global_load_lds(
      (const __attribute__((address_space(1))) void*)g,
      (__attribute__((address_space(3))) void*)l, 16, 0, 0);
}

// ---------------------------------------------------------------------------
// Transpose-cast: wt[n][k] = (bf16) w[k][n].  w is (K,N) fp32 row-major.
// ldt = dest row stride (allows K-padded dest).
// ---------------------------------------------------------------------------
__global__ __launch_bounds__(256)
void transpose_cast(const float* __restrict__ w, uint16_t* __restrict__ wt,
                    int K, int N, int ldt) {
  __shared__ float tile[32][33];
  int n0 = blockIdx.x * 32, k0 = blockIdx.y * 32;
  int tx = threadIdx.x & 31, ty = threadIdx.x >> 5;
#pragma unroll
  for (int it = 0; it < 4; ++it) {
    int r = ty + it * 8;
    tile[r][tx] = w[(size_t)(k0 + r) * N + n0 + tx];
  }
  __syncthreads();
#pragma unroll
  for (int it = 0; it < 4; ++it) {
    int r = ty + it * 8;
    wt[(size_t)(n0 + r) * ldt + k0 + tx] = f2bf(tile[tx][r]);
  }
}

// ---------------------------------------------------------------------------
// mod = silu(time_emb) @ mod_w + mod_b      (4 x 6144, K=1024)
// ---------------------------------------------------------------------------
__global__ __launch_bounds__(1024)
void mod_kernel(const float* __restrict__ te, const float* __restrict__ mw,
                const float* __restrict__ mb, float* __restrict__ mod) {
  __shared__ float ste[4096];
  __shared__ float red[4][4][256];
  int tid = threadIdx.x;
  for (int i = tid; i < 4096; i += 1024) { float v = te[i]; ste[i] = silu(v); }
  __syncthreads();
  int kslice = tid >> 8, cl = tid & 255;
  int col = blockIdx.x * 256 + cl;
  float acc[4] = {0.f, 0.f, 0.f, 0.f};
  for (int kk = 0; kk < 256; ++kk) {
    int k = kslice * 256 + kk;
    float wv = mw[k * 6144 + col];
#pragma unroll
    for (int b = 0; b < 4; ++b) acc[b] += ste[b * 1024 + k] * wv;
  }
#pragma unroll
  for (int b = 0; b < 4; ++b) red[kslice][b][cl] = acc[b];
  __syncthreads();
  if (kslice == 0) {
#pragma unroll
    for (int b = 0; b < 4; ++b)
      mod[b * 6144 + col] =
          red[0][b][cl] + red[1][b][cl] + red[2][b][cl] + red[3][b][cl] + mb[col];
  }
}

// ---------------------------------------------------------------------------
// RMSNorm + modulation -> bf16.  One block per row.
// ---------------------------------------------------------------------------
__global__ __launch_bounds__(256)
void norm_kernel(const float* __restrict__ xf,
                 const float* __restrict__ w, const float* __restrict__ mod,
                 int shift_off, int scale_off, uint16_t* __restrict__ out) {
  int row = blockIdx.x;
  int b = row >> 12;
  int tid = threadIdx.x;
  float4 t = *(const float4*)(xf + (size_t)row * 1024 + tid * 4);
  float v[4] = {t.x, t.y, t.z, t.w};
  float ss = v[0] * v[0] + v[1] * v[1] + v[2] * v[2] + v[3] * v[3];
#pragma unroll
  for (int off = 1; off < 64; off <<= 1) ss += __shfl_xor(ss, off);
  __shared__ float red[4];
  if ((tid & 63) == 0) red[tid >> 6] = ss;
  __syncthreads();
  float tot = red[0] + red[1] + red[2] + red[3];
  float rinv = rsqrtf(tot * (1.0f / 1024.0f) + 1e-6f);
  const float* mrow = mod + b * 6144;
  uint16_t o[4];
#pragma unroll
  for (int c = 0; c < 4; ++c) {
    int col = tid * 4 + c;
    float hv = v[c] * rinv * w[col] * (1.0f + mrow[scale_off + col]) + mrow[shift_off + col];
    o[c] = f2bf(hv);
  }
  uint2 pk;
  pk.x = (uint32_t)o[0] | ((uint32_t)o[1] << 16);
  pk.y = (uint32_t)o[2] | ((uint32_t)o[3] << 16);
  *(uint2*)(out + (size_t)row * 1024 + tid * 4) = pk;
}

// ---------------------------------------------------------------------------
// gemm256: C(M,Npad) = A(M,K)bf16 @ Bt(Npad,K)bf16. 256x256 tile, BK=64,
// 512 thr / 8 waves (2Mx4N), wave tile 128x64 = acc[8][4] f32x4.
// LDS 128 KB: As[2][256*64] + Bs[2][256*64] (dbuf). Rows = 64 elems, XOR-8
// swizzle: phys 16B-chunk p of row r holds logical chunk p^(r&7); staging
// applies the inverse on the global source (DMA dest stays linear).
// Schedule (per K-tile, 4 phases):
//   p1: rd A[i0-3,ks0](4) + B[ks0](4) | stage A0(t+1) | BAR lgkm0 16xMFMA BAR
//   p2: rd A[i4-7,ks0](4)             | stage A1(t+1) | BAR lgkm0 16xMFMA BAR
//   p3: rd A[i0-3,ks1](4) + B[ks1](4) |               | BAR lgkm0 16xMFMA BAR
//   p4: rd A[i4-7,ks1](4)             | stage B0B1(t+2)| BAR lgkm0 16xMFMA
//       vmcnt(4) BAR      <- counted: only B(t+2)'s 4 loads stay in flight
// B(t+2) targets the CURRENT slot's B region: safe, its last reader (p3)
// finished at p3's lgkm0+barrier. A(t+1) targets the other slot: always safe.
// XCD remap: xcd = bid&7; requires tiles_m % 8 == 0 (64 here).
// MODE: 0 store bf16 | 1 x+gate1*C fp32 | 2 silu bf16 | 3 h1*C bf16
//       4 xio += gate2*C (fp32 RMW)
// ---------------------------------------------------------------------------

#define BAR __builtin_amdgcn_s_barrier()
#define LGKM0                                            \
  do {                                                   \
    asm volatile("s_waitcnt lgkmcnt(0)" ::: "memory");   \
    __builtin_amdgcn_sched_barrier(0);                   \
  } while (0)
#define VMW(N) asm volatile("s_waitcnt vmcnt(" #N ")" ::: "memory")

#define GRD4(DST, BASE, ROWB, SWZ)                                           \
  {                                                                          \
    _Pragma("unroll") for (int q_ = 0; q_ < 4; ++q_)                         \
        DST[q_] = *(const bf16x8*)((BASE) + ((ROWB) + q_ * 16 + col) * 64 +  \
                                   (SWZ));                                   \
  }

#define MM16(I0, AF)                                                         \
  {                                                                          \
    __builtin_amdgcn_s_setprio(1);                                           \
    _Pragma("unroll") for (int q_ = 0; q_ < 4; ++q_) {                       \
      _Pragma("unroll") for (int j_ = 0; j_ < 4; ++j_)                       \
          acc[(I0) + q_][j_] = __builtin_amdgcn_mfma_f32_16x16x32_bf16(      \
              AF[q_], bf[j_], acc[(I0) + q_][j_], 0, 0, 0);                  \
    }                                                                        \
    __builtin_amdgcn_s_setprio(0);                                           \
  }

#define ADST(S, H, G) ((lds16_t*)As[(S)] + (H) * 8192 + (G) * 4096 + sdoff)
#define BDST(S, H, G) ((lds16_t*)Bs[(S)] + (H) * 8192 + (G) * 4096 + sdoff)

#define TILE(S, KA, KB, DO_A, DO_B, VMTAIL)                                  \
  {                                                                          \
    bf16x8 af[4], bf[4];                                                     \
    /* phase 1 */                                                            \
    GRD4(af, As[S], wm * 128, swz0);                                         \
    GRD4(bf, Bs[S], wn * 64, swz0);                                          \
    if (DO_A) {                                                              \
      gload16(aS00 + (KA), ADST((S) ^ 1, 0, 0));                             \
      gload16(aS01 + (KA), ADST((S) ^ 1, 0, 1));                             \
    }                                                                        \
    BAR; LGKM0;                                                              \
    MM16(0, af);                                                             \
    BAR;                                                                     \
    /* phase 2 */                                                            \
    GRD4(af, As[S], wm * 128 + 64, swz0);                                    \
    if (DO_A) {                                                              \
      gload16(aS10 + (KA), ADST((S) ^ 1, 1, 0));                             \
      gload16(aS11 + (KA), ADST((S) ^ 1, 1, 1));                             \
    }                                                                        \
    BAR; LGKM0;                                                              \
    MM16(4, af);                                                             \
    BAR;                                                                     \
    /* phase 3 */                                                            \
    GRD4(af, As[S], wm * 128, swz1);                                         \
    GRD4(bf, Bs[S], wn * 64, swz1);                                          \
    BAR; LGKM0;                                                              \
    MM16(0, af);                                                             \
    BAR;                                                                     \
    /* phase 4 */                                                            \
    GRD4(af, As[S], wm * 128 + 64, swz1);                                    \
    if (DO_B) {                                                              \
      gload16(bS00 + (KB), BDST(S, 0, 0));                                   \
      gload16(bS01 + (KB), BDST(S, 0, 1));                                   \
      gload16(bS10 + (KB), BDST(S, 1, 0));                                   \
      gload16(bS11 + (KB), BDST(S, 1, 1));                                   \
    }                                                                        \
    BAR; LGKM0;                                                              \
    MM16(4, af);                                                             \
    VMTAIL;                                                                  \
    BAR;                                                                     \
  }

template <int MODE>
__global__ __launch_bounds__(512)
void gemm256(const uint16_t* __restrict__ A, int lda,
             const uint16_t* __restrict__ Bt, int ldb,
             int N, int K, int ldc,
             uint16_t* __restrict__ obf, const float* __restrict__ xin,
             const float* __restrict__ mod, const uint16_t* __restrict__ h1,
             float* __restrict__ xio) {
  __shared__ uint16_t As[2][16384];   // 2 x 32 KB (256 rows x 64 k)
  __shared__ uint16_t Bs[2][16384];
  const int tiles_n = N >> 8;
  const int xcd = blockIdx.x & 7;
  const int bslot = blockIdx.x >> 3;
  const int tm = (bslot / tiles_n) * 8 + xcd;
  const int tn = bslot % tiles_n;
  const int m0 = tm * 256, n0 = tn * 256;
  const int tid = threadIdx.x;
  const int wave = tid >> 6, lane = tid & 63;
  const int wm = wave >> 2, wn = wave & 3;     // 2 x 4 wave grid
  const int col = lane & 15, quad = lane >> 4;
  const int c7 = col & 7;
  const int swz0 = (quad ^ c7) << 3;           // ks0 phys chunk
  const int swz1 = ((4 + quad) ^ c7) << 3;     // ks1
  const int sdoff = wave * 512 + lane * 8;     // LDS stage dest (linear)

  // staging source: wave w, load g covers 8 rows (g*8+w)*8.. ; lane covers
  // row +(lane>>3), phys chunk lane&7 -> logical chunk (lane&7)^(lane>>3)
  const int srl = lane >> 3;
  const int sl8 = ((lane & 7) ^ srl) << 3;
  const int rg0 = wave * 8 + srl;
  const int rg1 = 64 + wave * 8 + srl;
  const uint16_t* aS00 = A + (size_t)(m0 + rg0) * lda + sl8;
  const uint16_t* aS01 = A + (size_t)(m0 + rg1) * lda + sl8;
  const uint16_t* aS10 = A + (size_t)(m0 + 128 + rg0) * lda + sl8;
  const uint16_t* aS11 = A + (size_t)(m0 + 128 + rg1) * lda + sl8;
  const uint16_t* bS00 = Bt + (size_t)(n0 + rg0) * ldb + sl8;
  const uint16_t* bS01 = Bt + (size_t)(n0 + rg1) * ldb + sl8;
  const uint16_t* bS10 = Bt + (size_t)(n0 + 128 + rg0) * ldb + sl8;
  const uint16_t* bS11 = Bt + (size_t)(n0 + 128 + rg1) * ldb + sl8;

  f32x4 acc[8][4];
#pragma unroll
  for (int i = 0; i < 8; ++i)
#pragma unroll
    for (int j = 0; j < 4; ++j) acc[i][j] = (f32x4){0.f, 0.f, 0.f, 0.f};

  // prologue: B(0)+A(0) -> slot0, B(1) -> slot1 (12 loads); wait tile0 only
  gload16(bS00, BDST(0, 0, 0)); gload16(bS01, BDST(0, 0, 1));
  gload16(bS10, BDST(0, 1, 0)); gload16(bS11, BDST(0, 1, 1));
  gload16(aS00, ADST(0, 0, 0)); gload16(aS01, ADST(0, 0, 1));
  gload16(aS10, ADST(0, 1, 0)); gload16(aS11, ADST(0, 1, 1));
  gload16(bS00 + 64, BDST(1, 0, 0)); gload16(bS01 + 64, BDST(1, 0, 1));
  gload16(bS10 + 64, BDST(1, 1, 0)); gload16(bS11 + 64, BDST(1, 1, 1));
  VMW(4);
  BAR;

  const int NT = K >> 6;                 // even, >= 4 (16 or 44 here)
  int k0 = 0;
  for (int t = 0; t + 2 < NT; t += 2) {  // steady: tiles 0..NT-3
    TILE(0, k0 + 64, k0 + 128, true, true, VMW(4));
    TILE(1, k0 + 128, k0 + 192, true, true, VMW(4));
    k0 += 128;
  }
  // tail: tile NT-2 (stage A(NT-1), drain), tile NT-1 (no stage)
  TILE(0, k0 + 64, 0, true, false, VMW(0));
  TILE(1, 0, 0, false, false, (void)0);

  // epilogue: C frag layout col=lane&15, row=quad*4+reg (verified)
#pragma unroll
  for (int i = 0; i < 8; ++i) {
#pragma unroll
    for (int j = 0; j < 4; ++j) {
#pragma unroll
      for (int r = 0; r < 4; ++r) {
        int row = m0 + wm * 128 + i * 16 + quad * 4 + r;
        int cn = n0 + wn * 64 + j * 16 + col;
        float c = acc[i][j][r];
        if (MODE == 0) {
          obf[(size_t)row * ldc + cn] = f2bf(c);
        } else if (MODE == 1) {
          int b = row >> 12;
          size_t idx = (size_t)row * 1024 + cn;
          float g = mod[b * 6144 + 2048 + cn];
          xio[idx] = xin[idx] + g * c;
        } else if (MODE == 2) {
          obf[(size_t)row * ldc + cn] = f2bf(silu(c));
        } else if (MODE == 3) {
          size_t idx = (size_t)row * ldc + cn;
          obf[idx] = f2bf(bf2f(h1[idx]) * c);
        } else {  // MODE 4
          int b = row >> 12;
          size_t idx = (size_t)row * 1024 + cn;
          float g = mod[b * 6144 + 5120 + cn];
          xio[idx] = xio[idx] + g * c;
        }
      }
    }
  }
}

// ---------------------------------------------------------------------------
// Fused attention (unchanged, verified).
// ---------------------------------------------------------------------------
__global__ __launch_bounds__(256)
void attn_kernel(const uint16_t* __restrict__ qkv, uint16_t* __restrict__ out) {
  __shared__ uint16_t lds[32768];
  const int tid = threadIdx.x;
  const int bid = blockIdx.x;
  const int slice = bid >> 2, qc = bid & 3;
  const int bt = slice >> 4, h = slice & 15;
  const int row0 = bt * 256;
  const int wave = tid >> 6, lane = tid & 63;
  const int col = lane & 15, quad = lane >> 4;

  {
    int kr = tid;
    const uint16_t* kp = qkv + (size_t)(row0 + kr) * 3072 + 1024 + h * 64;
    uint16_t* ks = lds + kr * 64;
#pragma unroll
    for (int kc = 0; kc < 8; ++kc) {
      uint4 v = *(const uint4*)(kp + kc * 8);
      *(uint4*)(ks + ((kc ^ (kr & 7)) << 3)) = v;
    }
  }
  {
    int p = tid & 127, dh = tid >> 7;
    const uint16_t* vp0 = qkv + (size_t)(row0 + 2 * p) * 3072 + 2048 + h * 64 + dh * 32;
    const uint16_t* vp1 = vp0 + 3072;
    uint16_t r0[32], r1[32];
#pragma unroll
    for (int i = 0; i < 4; ++i) {
      *(uint4*)(r0 + i * 8) = *(const uint4*)(vp0 + i * 8);
      *(uint4*)(r1 + i * 8) = *(const uint4*)(vp1 + i * 8);
    }
    uint32_t* vt = (uint32_t*)(lds + 16384);
    int krc = p >> 2;
#pragma unroll
    for (int i = 0; i < 32; ++i) {
      int d = dh * 32 + i;
      uint32_t val = (uint32_t)r0[i] | ((uint32_t)r1[i] << 16);
      vt[d * 128 + ((krc ^ (d & 7)) << 2) + (p & 3)] = val;
    }
  }
  __syncthreads();

  const int qrow = qc * 64 + wave * 16 + col;
  const uint16_t* qp = qkv + (size_t)(row0 + qrow) * 3072 + h * 64;
  bf16x8 aq0 = *(const bf16x8*)(qp + quad * 8);
  bf16x8 aq1 = *(const bf16x8*)(qp + 32 + quad * 8);

  f32x4 sc[16];
#pragma unroll
  for (int t = 0; t < 16; ++t) {
    int n = t * 16 + col;
    const uint16_t* kb = lds + n * 64;
    bf16x8 b0 = *(const bf16x8*)(kb + ((quad ^ (n & 7)) << 3));
    bf16x8 b1 = *(const bf16x8*)(kb + (((4 + quad) ^ (n & 7)) << 3));
    f32x4 s = (f32x4){0.f, 0.f, 0.f, 0.f};
    s = __builtin_amdgcn_mfma_f32_16x16x32_bf16(aq0, b0, s, 0, 0, 0);
    s = __builtin_amdgcn_mfma_f32_16x16x32_bf16(aq1, b1, s, 0, 0, 0);
    sc[t] = s;
  }

  const float scale = 0.125f;
  float inv[4];
#pragma unroll
  for (int i = 0; i < 4; ++i) {
    float m = -1e30f;
#pragma unroll
    for (int t = 0; t < 16; ++t) m = fmaxf(m, sc[t][i]);
    m = fmaxf(m, __shfl_xor(m, 1));
    m = fmaxf(m, __shfl_xor(m, 2));
    m = fmaxf(m, __shfl_xor(m, 4));
    m = fmaxf(m, __shfl_xor(m, 8));
    m *= scale;
    float sum = 0.f;
#pragma unroll
    for (int t = 0; t < 16; ++t) {
      float p = __expf(sc[t][i] * scale - m);
      sc[t][i] = p;
      sum += p;
    }
    sum += __shfl_xor(sum, 1);
    sum += __shfl_xor(sum, 2);
    sum += __shfl_xor(sum, 4);
    sum += __shfl_xor(sum, 8);
    inv[i] = 1.0f / sum;
  }
  __syncthreads();

  uint16_t* P = lds + wave * 4096;
#pragma unroll
  for (int t = 0; t < 16; ++t) {
    int pcb = t * 2 + (col >> 3);
#pragma unroll
    for (int i = 0; i < 4; ++i) {
      int r = quad * 4 + i;
      P[r * 256 + ((pcb ^ (r & 7)) << 3) + (col & 7)] = f2bf(sc[t][i] * inv[i]);
    }
  }

  f32x4 o[4];
#pragma unroll
  for (int nt = 0; nt < 4; ++nt) o[nt] = (f32x4){0.f, 0.f, 0.f, 0.f};
  const uint16_t* Vt = lds + 16384;
#pragma unroll
  for (int c = 0; c < 8; ++c) {
    int pc = c * 4 + quad;
    bf16x8 ap = *(const bf16x8*)(P + col * 256 + ((pc ^ (col & 7)) << 3));
#pragma unroll
    for (int nt = 0; nt < 4; ++nt) {
      int d = nt * 16 + col;
      bf16x8 bv = *(const bf16x8*)(Vt + d * 256 + ((pc ^ (d & 7)) << 3));
      o[nt] = __builtin_amdgcn_mfma_f32_16x16x32_bf16(ap, bv, o[nt], 0, 0, 0);
    }
  }

#pragma unroll
  for (int nt = 0; nt < 4; ++nt) {
#pragma unroll
    for (int r = 0; r < 4; ++r) {
      int grow = row0 + qc * 64 + wave * 16 + quad * 4 + r;
      int gcol = h * 64 + nt * 16 + col;
      out[(size_t)grow * 1024 + gcol] = f2bf(o[nt][r]);
    }
  }
}

// ---------------------------------------------------------------------------
extern "C" void kernel_launch(void* const* d_in, const int* in_sizes, int n_in,
                              void* d_out, int out_size, void* d_ws, size_t ws_size,
                              hipStream_t stream) {
  const float* x        = (const float*)d_in[0];
  const float* time_emb = (const float*)d_in[1];
  const float* norm1_w  = (const float*)d_in[2];
  const float* norm2_w  = (const float*)d_in[3];
  const float* qkv_w    = (const float*)d_in[4];
  const float* out_w    = (const float*)d_in[5];
  const float* w1       = (const float*)d_in[6];
  const float* w2       = (const float*)d_in[7];
  const float* w3       = (const float*)d_in[8];
  const float* mod_w    = (const float*)d_in[9];
  const float* mod_b    = (const float*)d_in[10];
  float* out = (float*)d_out;

  // workspace layout (bytes):
  //   mod     @ 0         (98304)
  //   wqkv_t  @ 98304     (3072*1024*2  = 6291456)
  //   wout_t  @ 6389760   (1024*1024*2  = 2097152)
  //   w1t     @ 8486912   (2816*1024*2  = 5767168)  N-padded
  //   w2t     @ 14254080  (5767168)                 N-padded
  //   w3t     @ 20021248  (1024*2816*2  = 5767168)  K-padded
  //   hbuf    @ 25788416  (16384*1024*2 = 33554432)
  //   qkvb    @ 59342848  (16384*3072*2 = 100663296); hid aliases qkvb
  char* ws = (char*)d_ws;
  float*    mod    = (float*)(ws);
  uint16_t* wqkv_t = (uint16_t*)(ws + 98304);
  uint16_t* wout_t = (uint16_t*)(ws + 6389760);
  uint16_t* w1t    = (uint16_t*)(ws + 8486912);
  uint16_t* w2t    = (uint16_t*)(ws + 14254080);
  uint16_t* w3t    = (uint16_t*)(ws + 20021248);
  uint16_t* hbuf   = (uint16_t*)(ws + 25788416);
  uint16_t* qkvb   = (uint16_t*)(ws + 59342848);
  uint16_t* hid    = qkvb;

  // zero padded weight buffers (pad rows/cols must be 0, not garbage/NaN)
  hipMemsetAsync(w1t, 0, (size_t)2816 * 1024 * 2, stream);
  hipMemsetAsync(w2t, 0, (size_t)2816 * 1024 * 2, stream);
  hipMemsetAsync(w3t, 0, (size_t)1024 * 2816 * 2, stream);

  dim3 blk(256);
  transpose_cast<<<dim3(96, 32), blk, 0, stream>>>(qkv_w, wqkv_t, 1024, 3072, 1024);
  transpose_cast<<<dim3(32, 32), blk, 0, stream>>>(out_w, wout_t, 1024, 1024, 1024);
  transpose_cast<<<dim3(86, 32), blk, 0, stream>>>(w1, w1t, 1024, 2752, 1024);
  transpose_cast<<<dim3(86, 32), blk, 0, stream>>>(w2, w2t, 1024, 2752, 1024);
  transpose_cast<<<dim3(32, 86), blk, 0, stream>>>(w3, w3t, 2752, 1024, 2816);

  mod_kernel<<<24, 1024, 0, stream>>>(time_emb, mod_w, mod_b, mod);

  norm_kernel<<<16384, blk, 0, stream>>>(x, norm1_w, mod, 0, 1024, hbuf);

  // qkv = h @ qkv_w   (M=16384, N=3072, K=1024)
  gemm256<0><<<768, 512, 0, stream>>>(hbuf, 1024, wqkv_t, 1024, 3072, 1024, 3072,
                                      qkvb, nullptr, nullptr, nullptr, nullptr);
  attn_kernel<<<4096, blk, 0, stream>>>(qkvb, hbuf);

  // x1 = x + gate1 * (attn @ out_w) -> d_out (fp32)
  gemm256<1><<<256, 512, 0, stream>>>(hbuf, 1024, wout_t, 1024, 1024, 1024, 1024,
                                      nullptr, x, mod, nullptr, out);
  // h2 = rmsnorm(x1)*(1+scale2)+shift2
  norm_kernel<<<16384, blk, 0, stream>>>(out, norm2_w, mod, 3072, 4096, hbuf);

  // h1 = silu(h2 @ w1)   (Npad=2816, zero-padded -> silu(0)=0 in pad cols)
  gemm256<2><<<704, 512, 0, stream>>>(hbuf, 1024, w1t, 1024, 2816, 1024, 2816,
                                      hid, nullptr, nullptr, nullptr, nullptr);
  // hid = h1 * (h2 @ w2)   (in place; pad cols: 0 * C2 = 0)
  gemm256<3><<<704, 512, 0, stream>>>(hbuf, 1024, w2t, 1024, 2816, 1024, 2816,
                                      hid, nullptr, nullptr, hid, nullptr);
  // out = x1 + gate2 * (hid @ w3)   (fp32 RMW, Kpad=2816; pad contributes 0)
  gemm256<4><<<256, 512, 0, stream>>>(hid, 2816, w3t, 2816, 1024, 2816, 1024,
                                      nullptr, nullptr, mod, nullptr, out);
}

// Round 2
// 757.582 us; speedup vs baseline: 1.1377x; 1.1377x over previous
//
#include <hip/hip_runtime.h>
#include <stdint.h>

// ---------------------------------------------------------------------------
// TransformerBlock bf16 MFMA. OUTPUT FP32.
// Round 9: (1) inline-asm ds_read_b128 for all GEMM fragment loads — hides
// the LDS dependency from hipcc's hazard recognizer so it cannot insert its
// own s_waitcnt vmcnt(0) before LDS reads aliasing global_load_lds dests
// (suspected killer of the counted-vmcnt pipeline; round-8 perf == 2-phase
// ceiling). (2) w1+w2 fused into gemm_ffn (dual-B, silu(C1)*C2 epilogue):
// saves the 184 MB h1 round-trip and one dispatch. (3) sched_barrier(0)
// before epilogues to keep epilogue global loads out of the vmcnt window.
// ---------------------------------------------------------------------------

using bf16x8 = __attribute__((ext_vector_type(8))) short;
using f32x4  = __attribute__((ext_vector_type(4))) float;

typedef __attribute__((address_space(3))) uint16_t lds16_t;

__device__ __forceinline__ float bf2f(uint16_t h) {
  union { uint32_t u; float f; } v; v.u = ((uint32_t)h) << 16; return v.f;
}
__device__ __forceinline__ uint16_t f2bf(float f) {
  union { float f; uint32_t u; } v; v.f = f;
  uint32_t r = v.u + 0x7FFFu + ((v.u >> 16) & 1u);
  return (uint16_t)(r >> 16);
}
__device__ __forceinline__ float silu(float x) { return x / (1.0f + __expf(-x)); }

__device__ __forceinline__ void gload16(const uint16_t* g, lds16_t* l) {
  __builtin_amdgcn_global_load_lds(
      (const __attribute__((address_space(1))) void*)g,
      (__attribute__((address_space(3))) void*)l, 16, 0, 0);
}

// Inline-asm LDS read: compiler cannot see the LDS dependency, so it cannot
// insert conservative vmcnt waits against in-flight global_load_lds DMA.
// Ordering vs staged data is enforced by our explicit VMW/BAR/LGKM0 fences.
__device__ __forceinline__ bf16x8 lds_rd_b128(const uint16_t* p) {
  bf16x8 r;
  uint32_t a = (uint32_t)(uintptr_t)(const lds16_t*)p;
  asm volatile("ds_read_b128 %0, %1" : "=v"(r) : "v"(a) : "memory");
  return r;
}

// ---------------------------------------------------------------------------
// Transpose-cast: wt[n][k] = (bf16) w[k][n].  w is (K,N) fp32 row-major.
// ---------------------------------------------------------------------------
__global__ __launch_bounds__(256)
void transpose_cast(const float* __restrict__ w, uint16_t* __restrict__ wt,
                    int K, int N, int ldt) {
  __shared__ float tile[32][33];
  int n0 = blockIdx.x * 32, k0 = blockIdx.y * 32;
  int tx = threadIdx.x & 31, ty = threadIdx.x >> 5;
#pragma unroll
  for (int it = 0; it < 4; ++it) {
    int r = ty + it * 8;
    tile[r][tx] = w[(size_t)(k0 + r) * N + n0 + tx];
  }
  __syncthreads();
#pragma unroll
  for (int it = 0; it < 4; ++it) {
    int r = ty + it * 8;
    wt[(size_t)(n0 + r) * ldt + k0 + tx] = f2bf(tile[tx][r]);
  }
}

// ---------------------------------------------------------------------------
// mod = silu(time_emb) @ mod_w + mod_b      (4 x 6144, K=1024)
// ---------------------------------------------------------------------------
__global__ __launch_bounds__(1024)
void mod_kernel(const float* __restrict__ te, const float* __restrict__ mw,
                const float* __restrict__ mb, float* __restrict__ mod) {
  __shared__ float ste[4096];
  __shared__ float red[4][4][256];
  int tid = threadIdx.x;
  for (int i = tid; i < 4096; i += 1024) { float v = te[i]; ste[i] = silu(v); }
  __syncthreads();
  int kslice = tid >> 8, cl = tid & 255;
  int col = blockIdx.x * 256 + cl;
  float acc[4] = {0.f, 0.f, 0.f, 0.f};
  for (int kk = 0; kk < 256; ++kk) {
    int k = kslice * 256 + kk;
    float wv = mw[k * 6144 + col];
#pragma unroll
    for (int b = 0; b < 4; ++b) acc[b] += ste[b * 1024 + k] * wv;
  }
#pragma unroll
  for (int b = 0; b < 4; ++b) red[kslice][b][cl] = acc[b];
  __syncthreads();
  if (kslice == 0) {
#pragma unroll
    for (int b = 0; b < 4; ++b)
      mod[b * 6144 + col] =
          red[0][b][cl] + red[1][b][cl] + red[2][b][cl] + red[3][b][cl] + mb[col];
  }
}

// ---------------------------------------------------------------------------
// RMSNorm + modulation -> bf16.  One block per row.
// ---------------------------------------------------------------------------
__global__ __launch_bounds__(256)
void norm_kernel(const float* __restrict__ xf,
                 const float* __restrict__ w, const float* __restrict__ mod,
                 int shift_off, int scale_off, uint16_t* __restrict__ out) {
  int row = blockIdx.x;
  int b = row >> 12;
  int tid = threadIdx.x;
  float4 t = *(const float4*)(xf + (size_t)row * 1024 + tid * 4);
  float v[4] = {t.x, t.y, t.z, t.w};
  float ss = v[0] * v[0] + v[1] * v[1] + v[2] * v[2] + v[3] * v[3];
#pragma unroll
  for (int off = 1; off < 64; off <<= 1) ss += __shfl_xor(ss, off);
  __shared__ float red[4];
  if ((tid & 63) == 0) red[tid >> 6] = ss;
  __syncthreads();
  float tot = red[0] + red[1] + red[2] + red[3];
  float rinv = rsqrtf(tot * (1.0f / 1024.0f) + 1e-6f);
  const float* mrow = mod + b * 6144;
  uint16_t o[4];
#pragma unroll
  for (int c = 0; c < 4; ++c) {
    int col = tid * 4 + c;
    float hv = v[c] * rinv * w[col] * (1.0f + mrow[scale_off + col]) + mrow[shift_off + col];
    o[c] = f2bf(hv);
  }
  uint2 pk;
  pk.x = (uint32_t)o[0] | ((uint32_t)o[1] << 16);
  pk.y = (uint32_t)o[2] | ((uint32_t)o[3] << 16);
  *(uint2*)(out + (size_t)row * 1024 + tid * 4) = pk;
}

// ---------------------------------------------------------------------------
// Shared GEMM machinery (8-phase, counted vmcnt, XOR-8 LDS swizzle).
// ---------------------------------------------------------------------------
#define BAR __builtin_amdgcn_s_barrier()
#define LGKM0                                            \
  do {                                                   \
    asm volatile("s_waitcnt lgkmcnt(0)" ::: "memory");   \
    __builtin_amdgcn_sched_barrier(0);                   \
  } while (0)
#define VMW(N) asm volatile("s_waitcnt vmcnt(" #N ")" ::: "memory")

#define GRD4(DST, BASE, ROWB, SWZ)                                           \
  {                                                                          \
    _Pragma("unroll") for (int q_ = 0; q_ < 4; ++q_)                         \
        DST[q_] = lds_rd_b128((BASE) + ((ROWB) + q_ * 16 + col) * 64 +       \
                              (SWZ));                                        \
  }

// ---------------------------------------------------------------------------
// gemm256: C(M,Npad) = A(M,K)bf16 @ Bt(Npad,K)bf16. 256x256 tile, BK=64,
// 512 thr / 8 waves (2Mx4N), wave tile 128x64. LDS 128 KB dbuf, XOR-8 swz.
// Schedule per K-tile: 4 phases {asm ds_read || stage -> BAR -> lgkm0 ->
// setprio 16xMFMA -> BAR}; A(t+1) staged p1/p2 (other slot), B(t+2) staged
// p4 (current slot, safe after p3's end-barrier); single counted VMW(4).
// MODE: 0 store bf16 | 1 x+gate1*C fp32 | 4 xio += gate2*C (fp32 RMW)
// ---------------------------------------------------------------------------
#define MM16(I0, AF)                                                         \
  {                                                                          \
    __builtin_amdgcn_s_setprio(1);                                           \
    _Pragma("unroll") for (int q_ = 0; q_ < 4; ++q_) {                       \
      _Pragma("unroll") for (int j_ = 0; j_ < 4; ++j_)                       \
          acc[(I0) + q_][j_] = __builtin_amdgcn_mfma_f32_16x16x32_bf16(      \
              AF[q_], bf[j_], acc[(I0) + q_][j_], 0, 0, 0);                  \
    }                                                                        \
    __builtin_amdgcn_s_setprio(0);                                           \
  }

#define ADST(S, H, G) ((lds16_t*)As[(S)] + (H) * 8192 + (G) * 4096 + sdoff)
#define BDST(S, H, G) ((lds16_t*)Bs[(S)] + (H) * 8192 + (G) * 4096 + sdoff)

#define TILE(S, KA, KB, DO_A, DO_B, VMTAIL)                                  \
  {                                                                          \
    bf16x8 af[4], bf[4];                                                     \
    /* phase 1 */                                                            \
    GRD4(af, As[S], wm * 128, swz0);                                         \
    GRD4(bf, Bs[S], wn * 64, swz0);                                          \
    if (DO_A) {                                                              \
      gload16(aS00 + (KA), ADST((S) ^ 1, 0, 0));                             \
      gload16(aS01 + (KA), ADST((S) ^ 1, 0, 1));                             \
    }                                                                        \
    BAR; LGKM0;                                                              \
    MM16(0, af);                                                             \
    BAR;                                                                     \
    /* phase 2 */                                                            \
    GRD4(af, As[S], wm * 128 + 64, swz0);                                    \
    if (DO_A) {                                                              \
      gload16(aS10 + (KA), ADST((S) ^ 1, 1, 0));                             \
      gload16(aS11 + (KA), ADST((S) ^ 1, 1, 1));                             \
    }                                                                        \
    BAR; LGKM0;                                                              \
    MM16(4, af);                                                             \
    BAR;                                                                     \
    /* phase 3 */                                                            \
    GRD4(af, As[S], wm * 128, swz1);                                         \
    GRD4(bf, Bs[S], wn * 64, swz1);                                          \
    BAR; LGKM0;                                                              \
    MM16(0, af);                                                             \
    BAR;                                                                     \
    /* phase 4 */                                                            \
    GRD4(af, As[S], wm * 128 + 64, swz1);                                    \
    if (DO_B) {                                                              \
      gload16(bS00 + (KB), BDST(S, 0, 0));                                   \
      gload16(bS01 + (KB), BDST(S, 0, 1));                                   \
      gload16(bS10 + (KB), BDST(S, 1, 0));                                   \
      gload16(bS11 + (KB), BDST(S, 1, 1));                                   \
    }                                                                        \
    BAR; LGKM0;                                                              \
    MM16(4, af);                                                             \
    VMTAIL;                                                                  \
    BAR;                                                                     \
  }

template <int MODE>
__global__ __launch_bounds__(512)
void gemm256(const uint16_t* __restrict__ A, int lda,
             const uint16_t* __restrict__ Bt, int ldb,
             int N, int K, int ldc,
             uint16_t* __restrict__ obf, const float* __restrict__ xin,
             const float* __restrict__ mod, const uint16_t* __restrict__ h1,
             float* __restrict__ xio) {
  __shared__ uint16_t As[2][16384];   // 2 x 32 KB (256 rows x 64 k)
  __shared__ uint16_t Bs[2][16384];
  const int tiles_n = N >> 8;
  const int xcd = blockIdx.x & 7;
  const int bslot = blockIdx.x >> 3;
  const int tm = (bslot / tiles_n) * 8 + xcd;
  const int tn = bslot % tiles_n;
  const int m0 = tm * 256, n0 = tn * 256;
  const int tid = threadIdx.x;
  const int wave = tid >> 6, lane = tid & 63;
  const int wm = wave >> 2, wn = wave & 3;     // 2 x 4 wave grid
  const int col = lane & 15, quad = lane >> 4;
  const int c7 = col & 7;
  const int swz0 = (quad ^ c7) << 3;           // ks0 phys chunk
  const int swz1 = ((4 + quad) ^ c7) << 3;     // ks1
  const int sdoff = wave * 512 + lane * 8;     // LDS stage dest (linear)

  const int srl = lane >> 3;
  const int sl8 = ((lane & 7) ^ srl) << 3;
  const int rg0 = wave * 8 + srl;
  const int rg1 = 64 + wave * 8 + srl;
  const uint16_t* aS00 = A + (size_t)(m0 + rg0) * lda + sl8;
  const uint16_t* aS01 = A + (size_t)(m0 + rg1) * lda + sl8;
  const uint16_t* aS10 = A + (size_t)(m0 + 128 + rg0) * lda + sl8;
  const uint16_t* aS11 = A + (size_t)(m0 + 128 + rg1) * lda + sl8;
  const uint16_t* bS00 = Bt + (size_t)(n0 + rg0) * ldb + sl8;
  const uint16_t* bS01 = Bt + (size_t)(n0 + rg1) * ldb + sl8;
  const uint16_t* bS10 = Bt + (size_t)(n0 + 128 + rg0) * ldb + sl8;
  const uint16_t* bS11 = Bt + (size_t)(n0 + 128 + rg1) * ldb + sl8;

  f32x4 acc[8][4];
#pragma unroll
  for (int i = 0; i < 8; ++i)
#pragma unroll
    for (int j = 0; j < 4; ++j) acc[i][j] = (f32x4){0.f, 0.f, 0.f, 0.f};

  // prologue: B(0)+A(0) -> slot0, B(1) -> slot1 (12 loads); wait tile0 only
  gload16(bS00, BDST(0, 0, 0)); gload16(bS01, BDST(0, 0, 1));
  gload16(bS10, BDST(0, 1, 0)); gload16(bS11, BDST(0, 1, 1));
  gload16(aS00, ADST(0, 0, 0)); gload16(aS01, ADST(0, 0, 1));
  gload16(aS10, ADST(0, 1, 0)); gload16(aS11, ADST(0, 1, 1));
  gload16(bS00 + 64, BDST(1, 0, 0)); gload16(bS01 + 64, BDST(1, 0, 1));
  gload16(bS10 + 64, BDST(1, 1, 0)); gload16(bS11 + 64, BDST(1, 1, 1));
  VMW(4);
  BAR;

  const int NT = K >> 6;                 // even, >= 4 (16 or 44 here)
  int k0 = 0;
  for (int t = 0; t + 2 < NT; t += 2) {  // steady: tiles 0..NT-3
    TILE(0, k0 + 64, k0 + 128, true, true, VMW(4));
    TILE(1, k0 + 128, k0 + 192, true, true, VMW(4));
    k0 += 128;
  }
  // tail: tile NT-2 (stage A(NT-1), drain), tile NT-1 (no stage)
  TILE(0, k0 + 64, 0, true, false, VMW(0));
  TILE(1, 0, 0, false, false, (void)0);

  __builtin_amdgcn_sched_barrier(0);   // keep epilogue loads out of K-loop

  // epilogue: C frag layout col=lane&15, row=quad*4+reg (verified)
#pragma unroll
  for (int i = 0; i < 8; ++i) {
#pragma unroll
    for (int j = 0; j < 4; ++j) {
#pragma unroll
      for (int r = 0; r < 4; ++r) {
        int row = m0 + wm * 128 + i * 16 + quad * 4 + r;
        int cn = n0 + wn * 64 + j * 16 + col;
        float c = acc[i][j][r];
        if (MODE == 0) {
          obf[(size_t)row * ldc + cn] = f2bf(c);
        } else if (MODE == 1) {
          int b = row >> 12;
          size_t idx = (size_t)row * 1024 + cn;
          float g = mod[b * 6144 + 2048 + cn];
          xio[idx] = xin[idx] + g * c;
        } else {  // MODE 4
          int b = row >> 12;
          size_t idx = (size_t)row * 1024 + cn;
          float g = mod[b * 6144 + 5120 + cn];
          xio[idx] = xio[idx] + g * c;
        }
      }
    }
  }
}

// ---------------------------------------------------------------------------
// gemm_ffn: fused FFN up-projection.  out = f2bf(silu(A@B1^T) * (A@B2^T)).
// A (16384,1024) bf16; B1t/B2t (2816,1024) bf16; out (16384,2816) bf16.
// BM=256, BN=128 (per output), K=1024 (NT=16). 8 waves 4Mx2N, wave 64x64
// per output, dual acc (2 x 16 f32x4 = 128 VGPR). LDS 128 KB:
// As[2][256*64] + B1s[2][128*64] + B2s[2][128*64].
// Staging (race-audited):
//   p1: A(u+1) h0,h1 + B2(u+1) -> slot^1   [slot^1 fully read by u-1 end]
//   p2: A(u+1) h2,h3            -> slot^1
//   p4: B1(u+2)                 -> slot     [B1[S] last read p3, done by its
//                                            end-barrier -> safe pre-BAR]
//   p4 end: VMW(2)  (retires A(u+1)+B2(u+1)+B1(u+1); leaves B1(u+2) flying)
// ---------------------------------------------------------------------------
#define MMF(ACC, AF, BF)                                                     \
  {                                                                          \
    __builtin_amdgcn_s_setprio(1);                                           \
    _Pragma("unroll") for (int i_ = 0; i_ < 4; ++i_) {                       \
      _Pragma("unroll") for (int j_ = 0; j_ < 4; ++j_)                       \
          ACC[i_][j_] = __builtin_amdgcn_mfma_f32_16x16x32_bf16(             \
              AF[i_], BF[j_], ACC[i_][j_], 0, 0, 0);                         \
    }                                                                        \
    __builtin_amdgcn_s_setprio(0);                                           \
  }

#define FAD(S, H)  ((lds16_t*)As[(S)]  + (H) * 4096 + sdoff)
#define FB1D(S, H) ((lds16_t*)B1s[(S)] + (H) * 4096 + sdoff)
#define FB2D(S, H) ((lds16_t*)B2s[(S)] + (H) * 4096 + sdoff)

#define FTILE(S, KN, KB, DO_AB2, DO_B1, VMTAIL)                              \
  {                                                                          \
    bf16x8 af[4], bb[4];                                                     \
    /* p1: A ks0 + B1 ks0 | stage A(u+1) h0,h1 + B2(u+1) */                  \
    GRD4(af, As[S], wm * 64, swz0);                                          \
    GRD4(bb, B1s[S], wn * 64, swz0);                                         \
    if (DO_AB2) {                                                            \
      gload16(aS[0] + (KN), FAD((S) ^ 1, 0));                                \
      gload16(aS[1] + (KN), FAD((S) ^ 1, 1));                                \
      gload16(b2S[0] + (KN), FB2D((S) ^ 1, 0));                              \
      gload16(b2S[1] + (KN), FB2D((S) ^ 1, 1));                              \
    }                                                                        \
    BAR; LGKM0;                                                              \
    MMF(acc1, af, bb);                                                       \
    BAR;                                                                     \
    /* p2: B2 ks0 | stage A(u+1) h2,h3 */                                    \
    GRD4(bb, B2s[S], wn * 64, swz0);                                         \
    if (DO_AB2) {                                                            \
      gload16(aS[2] + (KN), FAD((S) ^ 1, 2));                                \
      gload16(aS[3] + (KN), FAD((S) ^ 1, 3));                                \
    }                                                                        \
    BAR; LGKM0;                                                              \
    MMF(acc2, af, bb);                                                       \
    BAR;                                                                     \
    /* p3: A ks1 + B1 ks1 */                                                 \
    GRD4(af, As[S], wm * 64, swz1);                                          \
    GRD4(bb, B1s[S], wn * 64, swz1);                                         \
    BAR; LGKM0;                                                              \
    MMF(acc1, af, bb);                                                       \
    BAR;                                                                     \
    /* p4: B2 ks1 | stage B1(u+2) */                                         \
    GRD4(bb, B2s[S], wn * 64, swz1);                                         \
    if (DO_B1) {                                                             \
      gload16(b1S[0] + (KB), FB1D(S, 0));                                    \
      gload16(b1S[1] + (KB), FB1D(S, 1));                                    \
    }                                                                        \
    BAR; LGKM0;                                                              \
    MMF(acc2, af, bb);                                                       \
    VMTAIL;                                                                  \
    BAR;                                                                     \
  }

__global__ __launch_bounds__(512)
void gemm_ffn(const uint16_t* __restrict__ A, const uint16_t* __restrict__ B1t,
              const uint16_t* __restrict__ B2t, uint16_t* __restrict__ outp) {
  __shared__ uint16_t As[2][16384];    // 256 x 64
  __shared__ uint16_t B1s[2][8192];    // 128 x 64
  __shared__ uint16_t B2s[2][8192];
  const int lda = 1024, ldb = 1024, ldc = 2816;
  const int tiles_n = 22;
  const int xcd = blockIdx.x & 7;
  const int bslot = blockIdx.x >> 3;
  const int tm = (bslot / tiles_n) * 8 + xcd;
  const int tn = bslot % tiles_n;
  const int m0 = tm * 256, n0 = tn * 128;
  const int tid = threadIdx.x;
  const int wave = tid >> 6, lane = tid & 63;
  const int wm = wave >> 1, wn = wave & 1;     // 4 x 2 wave grid, 64x64 tile
  const int col = lane & 15, quad = lane >> 4;
  const int c7 = col & 7;
  const int swz0 = (quad ^ c7) << 3;
  const int swz1 = ((4 + quad) ^ c7) << 3;
  const int sdoff = wave * 512 + lane * 8;
  const int srl = lane >> 3;
  const int sl8 = ((lane & 7) ^ srl) << 3;
  const int rg = wave * 8 + srl;

  const uint16_t* aS[4];
#pragma unroll
  for (int h = 0; h < 4; ++h)
    aS[h] = A + (size_t)(m0 + h * 64 + rg) * lda + sl8;
  const uint16_t* b1S[2]; const uint16_t* b2S[2];
#pragma unroll
  for (int h = 0; h < 2; ++h) {
    b1S[h] = B1t + (size_t)(n0 + h * 64 + rg) * ldb + sl8;
    b2S[h] = B2t + (size_t)(n0 + h * 64 + rg) * ldb + sl8;
  }

  f32x4 acc1[4][4], acc2[4][4];
#pragma unroll
  for (int i = 0; i < 4; ++i)
#pragma unroll
    for (int j = 0; j < 4; ++j) {
      acc1[i][j] = (f32x4){0.f, 0.f, 0.f, 0.f};
      acc2[i][j] = (f32x4){0.f, 0.f, 0.f, 0.f};
    }

  // prologue: A(0),B1(0),B2(0) -> slot0; B1(1) -> slot1 (10 loads)
#pragma unroll
  for (int h = 0; h < 4; ++h) gload16(aS[h], FAD(0, h));
  gload16(b1S[0], FB1D(0, 0)); gload16(b1S[1], FB1D(0, 1));
  gload16(b2S[0], FB2D(0, 0)); gload16(b2S[1], FB2D(0, 1));
  gload16(b1S[0] + 64, FB1D(1, 0)); gload16(b1S[1] + 64, FB1D(1, 1));
  VMW(2);
  BAR;

  int k0 = 0;
  for (int t = 0; t + 2 < 16; t += 2) {   // tiles 0..13
    FTILE(0, k0 + 64, k0 + 128, true, true, VMW(2));
    FTILE(1, k0 + 128, k0 + 192, true, true, VMW(2));
    k0 += 128;
  }
  // tail: tile 14 (stage A(15)+B2(15), drain), tile 15 (no stage)
  FTILE(0, k0 + 64, 0, true, false, VMW(0));
  FTILE(1, 0, 0, false, false, (void)0);

  __builtin_amdgcn_sched_barrier(0);

#pragma unroll
  for (int i = 0; i < 4; ++i) {
#pragma unroll
    for (int j = 0; j < 4; ++j) {
#pragma unroll
      for (int r = 0; r < 4; ++r) {
        int row = m0 + wm * 64 + i * 16 + quad * 4 + r;
        int cn = n0 + wn * 64 + j * 16 + col;
        float c1 = acc1[i][j][r];
        float c2 = acc2[i][j][r];
        outp[(size_t)row * ldc + cn] = f2bf(silu(c1) * c2);
      }
    }
  }
}

// ---------------------------------------------------------------------------
// Fused attention (unchanged, verified).
// ---------------------------------------------------------------------------
__global__ __launch_bounds__(256)
void attn_kernel(const uint16_t* __restrict__ qkv, uint16_t* __restrict__ out) {
  __shared__ uint16_t lds[32768];
  const int tid = threadIdx.x;
  const int bid = blockIdx.x;
  const int slice = bid >> 2, qc = bid & 3;
  const int bt = slice >> 4, h = slice & 15;
  const int row0 = bt * 256;
  const int wave = tid >> 6, lane = tid & 63;
  const int col = lane & 15, quad = lane >> 4;

  {
    int kr = tid;
    const uint16_t* kp = qkv + (size_t)(row0 + kr) * 3072 + 1024 + h * 64;
    uint16_t* ks = lds + kr * 64;
#pragma unroll
    for (int kc = 0; kc < 8; ++kc) {
      uint4 v = *(const uint4*)(kp + kc * 8);
      *(uint4*)(ks + ((kc ^ (kr & 7)) << 3)) = v;
    }
  }
  {
    int p = tid & 127, dh = tid >> 7;
    const uint16_t* vp0 = qkv + (size_t)(row0 + 2 * p) * 3072 + 2048 + h * 64 + dh * 32;
    const uint16_t* vp1 = vp0 + 3072;
    uint16_t r0[32], r1[32];
#pragma unroll
    for (int i = 0; i < 4; ++i) {
      *(uint4*)(r0 + i * 8) = *(const uint4*)(vp0 + i * 8);
      *(uint4*)(r1 + i * 8) = *(const uint4*)(vp1 + i * 8);
    }
    uint32_t* vt = (uint32_t*)(lds + 16384);
    int krc = p >> 2;
#pragma unroll
    for (int i = 0; i < 32; ++i) {
      int d = dh * 32 + i;
      uint32_t val = (uint32_t)r0[i] | ((uint32_t)r1[i] << 16);
      vt[d * 128 + ((krc ^ (d & 7)) << 2) + (p & 3)] = val;
    }
  }
  __syncthreads();

  const int qrow = qc * 64 + wave * 16 + col;
  const uint16_t* qp = qkv + (size_t)(row0 + qrow) * 3072 + h * 64;
  bf16x8 aq0 = *(const bf16x8*)(qp + quad * 8);
  bf16x8 aq1 = *(const bf16x8*)(qp + 32 + quad * 8);

  f32x4 sc[16];
#pragma unroll
  for (int t = 0; t < 16; ++t) {
    int n = t * 16 + col;
    const uint16_t* kb = lds + n * 64;
    bf16x8 b0 = *(const bf16x8*)(kb + ((quad ^ (n & 7)) << 3));
    bf16x8 b1 = *(const bf16x8*)(kb + (((4 + quad) ^ (n & 7)) << 3));
    f32x4 s = (f32x4){0.f, 0.f, 0.f, 0.f};
    s = __builtin_amdgcn_mfma_f32_16x16x32_bf16(aq0, b0, s, 0, 0, 0);
    s = __builtin_amdgcn_mfma_f32_16x16x32_bf16(aq1, b1, s, 0, 0, 0);
    sc[t] = s;
  }

  const float scale = 0.125f;
  float inv[4];
#pragma unroll
  for (int i = 0; i < 4; ++i) {
    float m = -1e30f;
#pragma unroll
    for (int t = 0; t < 16; ++t) m = fmaxf(m, sc[t][i]);
    m = fmaxf(m, __shfl_xor(m, 1));
    m = fmaxf(m, __shfl_xor(m, 2));
    m = fmaxf(m, __shfl_xor(m, 4));
    m = fmaxf(m, __shfl_xor(m, 8));
    m *= scale;
    float sum = 0.f;
#pragma unroll
    for (int t = 0; t < 16; ++t) {
      float p = __expf(sc[t][i] * scale - m);
      sc[t][i] = p;
      sum += p;
    }
    sum += __shfl_xor(sum, 1);
    sum += __shfl_xor(sum, 2);
    sum += __shfl_xor(sum, 4);
    sum += __shfl_xor(sum, 8);
    inv[i] = 1.0f / sum;
  }
  __syncthreads();

  uint16_t* P = lds + wave * 4096;
#pragma unroll
  for (int t = 0; t < 16; ++t) {
    int pcb = t * 2 + (col >> 3);
#pragma unroll
    for (int i = 0; i < 4; ++i) {
      int r = quad * 4 + i;
      P[r * 256 + ((pcb ^ (r & 7)) << 3) + (col & 7)] = f2bf(sc[t][i] * inv[i]);
    }
  }

  f32x4 o[4];
#pragma unroll
  for (int nt = 0; nt < 4; ++nt) o[nt] = (f32x4){0.f, 0.f, 0.f, 0.f};
  const uint16_t* Vt = lds + 16384;
#pragma unroll
  for (int c = 0; c < 8; ++c) {
    int pc = c * 4 + quad;
    bf16x8 ap = *(const bf16x8*)(P + col * 256 + ((pc ^ (col & 7)) << 3));
#pragma unroll
    for (int nt = 0; nt < 4; ++nt) {
      int d = nt * 16 + col;
      bf16x8 bv = *(const bf16x8*)(Vt + d * 256 + ((pc ^ (d & 7)) << 3));
      o[nt] = __builtin_amdgcn_mfma_f32_16x16x32_bf16(ap, bv, o[nt], 0, 0, 0);
    }
  }

#pragma unroll
  for (int nt = 0; nt < 4; ++nt) {
#pragma unroll
    for (int r = 0; r < 4; ++r) {
      int grow = row0 + qc * 64 + wave * 16 + quad * 4 + r;
      int gcol = h * 64 + nt * 16 + col;
      out[(size_t)grow * 1024 + gcol] = f2bf(o[nt][r]);
    }
  }
}

// ---------------------------------------------------------------------------
extern "C" void kernel_launch(void* const* d_in, const int* in_sizes, int n_in,
                              void* d_out, int out_size, void* d_ws, size_t ws_size,
                              hipStream_t stream) {
  const float* x        = (const float*)d_in[0];
  const float* time_emb = (const float*)d_in[1];
  const float* norm1_w  = (const float*)d_in[2];
  const float* norm2_w  = (const float*)d_in[3];
  const float* qkv_w    = (const float*)d_in[4];
  const float* out_w    = (const float*)d_in[5];
  const float* w1       = (const float*)d_in[6];
  const float* w2       = (const float*)d_in[7];
  const float* w3       = (const float*)d_in[8];
  const float* mod_w    = (const float*)d_in[9];
  const float* mod_b    = (const float*)d_in[10];
  float* out = (float*)d_out;

  // workspace layout (bytes):
  //   mod     @ 0         (98304)
  //   wqkv_t  @ 98304     (3072*1024*2  = 6291456)
  //   wout_t  @ 6389760   (1024*1024*2  = 2097152)
  //   w1t     @ 8486912   (2816*1024*2  = 5767168)  N-padded
  //   w2t     @ 14254080  (5767168)                 N-padded
  //   w3t     @ 20021248  (1024*2816*2  = 5767168)  K-padded
  //   hbuf    @ 25788416  (16384*1024*2 = 33554432)
  //   qkvb    @ 59342848  (16384*3072*2 = 100663296); hid aliases qkvb
  char* ws = (char*)d_ws;
  float*    mod    = (float*)(ws);
  uint16_t* wqkv_t = (uint16_t*)(ws + 98304);
  uint16_t* wout_t = (uint16_t*)(ws + 6389760);
  uint16_t* w1t    = (uint16_t*)(ws + 8486912);
  uint16_t* w2t    = (uint16_t*)(ws + 14254080);
  uint16_t* w3t    = (uint16_t*)(ws + 20021248);
  uint16_t* hbuf   = (uint16_t*)(ws + 25788416);
  uint16_t* qkvb   = (uint16_t*)(ws + 59342848);
  uint16_t* hid    = qkvb;

  // zero padded weight buffers (pad rows/cols must be 0, not garbage/NaN)
  hipMemsetAsync(w1t, 0, (size_t)2816 * 1024 * 2, stream);
  hipMemsetAsync(w2t, 0, (size_t)2816 * 1024 * 2, stream);
  hipMemsetAsync(w3t, 0, (size_t)1024 * 2816 * 2, stream);

  dim3 blk(256);
  transpose_cast<<<dim3(96, 32), blk, 0, stream>>>(qkv_w, wqkv_t, 1024, 3072, 1024);
  transpose_cast<<<dim3(32, 32), blk, 0, stream>>>(out_w, wout_t, 1024, 1024, 1024);
  transpose_cast<<<dim3(86, 32), blk, 0, stream>>>(w1, w1t, 1024, 2752, 1024);
  transpose_cast<<<dim3(86, 32), blk, 0, stream>>>(w2, w2t, 1024, 2752, 1024);
  transpose_cast<<<dim3(32, 86), blk, 0, stream>>>(w3, w3t, 2752, 1024, 2816);

  mod_kernel<<<24, 1024, 0, stream>>>(time_emb, mod_w, mod_b, mod);

  norm_kernel<<<16384, blk, 0, stream>>>(x, norm1_w, mod, 0, 1024, hbuf);

  // qkv = h @ qkv_w   (M=16384, N=3072, K=1024)
  gemm256<0><<<768, 512, 0, stream>>>(hbuf, 1024, wqkv_t, 1024, 3072, 1024, 3072,
                                      qkvb, nullptr, nullptr, nullptr, nullptr);
  attn_kernel<<<4096, blk, 0, stream>>>(qkvb, hbuf);

  // x1 = x + gate1 * (attn @ out_w) -> d_out (fp32)
  gemm256<1><<<256, 512, 0, stream>>>(hbuf, 1024, wout_t, 1024, 1024, 1024, 1024,
                                      nullptr, x, mod, nullptr, out);
  // h2 = rmsnorm(x1)*(1+scale2)+shift2
  norm_kernel<<<16384, blk, 0, stream>>>(out, norm2_w, mod, 3072, 4096, hbuf);

  // hid = silu(h2 @ w1) * (h2 @ w2)   (fused dual-B, Npad=2816)
  gemm_ffn<<<1408, 512, 0, stream>>>(hbuf, w1t, w2t, hid);

  // out = x1 + gate2 * (hid @ w3)   (fp32 RMW, Kpad=2816; pad contributes 0)
  gemm256<4><<<256, 512, 0, stream>>>(hid, 2816, w3t, 2816, 1024, 2816, 1024,
                                      nullptr, nullptr, mod, nullptr, out);
}